// Round 1
// baseline (489.289 us; speedup 1.0000x reference)
//
#include <hip/hip_runtime.h>

// WindowAttention: B=256 windows, N=256 tokens, C=384, 12 heads, d=32.
// Pipeline: K0 cast weights->bf16 | K1 transpose-cast x (B,C,N)f32 -> xt (B*N,C)bf16
//           K2 per-(b,h): qkv MFMA GEMM + l2norm + MFMA attention -> attn (B*N,C)bf16
//           K3 proj MFMA GEMM + output transpose -> (B,C,N) f32
// MFMA 16x16x32 bf16 layouts (verified m89/m91/m120):
//   A: A[m][k] m=lane&15, k=(lane>>4)*8+j ; B: B[k][n] n=lane&15, k=(lane>>4)*8+j
//   D: col=lane&15, row=(lane>>4)*4+r
// Softmax: logits = SCALE*(qhat.khat) in [-0.178,0.178] -> no max-subtract needed,
// clip(1e-6,1) provably no-op (probs in [2.7e-3, 5.5e-3]).

#define DIM 384
#define NT 256
#define NH 12
#define HD 32
#define SCALE 0.17677669529663687f

typedef __bf16 bf16;
typedef __bf16 bf16x8 __attribute__((ext_vector_type(8)));
typedef float f32x4 __attribute__((ext_vector_type(4)));

#define MFMA16(a, b, c) __builtin_amdgcn_mfma_f32_16x16x32_bf16(a, b, c, 0, 0, 0)

// ---------------- K0: cast weights to bf16 ----------------
__global__ void k_cast_w(const float* __restrict__ qkv_w, const float* __restrict__ proj_w,
                         bf16* __restrict__ wq, bf16* __restrict__ wp) {
    int i = blockIdx.x * 256 + threadIdx.x;
    if (i < 3 * DIM * DIM) wq[i] = (bf16)qkv_w[i];
    if (i < DIM * DIM)     wp[i] = (bf16)proj_w[i];
}

// ---------------- K1: x (B,C,N) f32 -> xt (B*N, C) bf16 ----------------
__global__ void k_transpose_cast(const float* __restrict__ x, bf16* __restrict__ xt) {
    __shared__ float tile[32][33];
    int b = blockIdx.z;
    int c0 = blockIdx.y * 32;
    int n0 = blockIdx.x * 32;
    int tx = threadIdx.x, ty = threadIdx.y;
    const float* xp = x + (size_t)b * DIM * NT;
#pragma unroll
    for (int i = 0; i < 4; ++i) {
        int c = c0 + ty + i * 8;
        tile[ty + i * 8][tx] = xp[(size_t)c * NT + n0 + tx];
    }
    __syncthreads();
    bf16* op = xt + (size_t)b * NT * DIM;
#pragma unroll
    for (int i = 0; i < 4; ++i) {
        int n = n0 + ty + i * 8;
        op[(size_t)n * DIM + c0 + tx] = (bf16)tile[tx][ty + i * 8];
    }
}

// ---------------- K2: fused qkv GEMM + l2norm + attention, one block per (b,h) ----------------
__launch_bounds__(256, 2)
__global__ void k_qkv_attn(const bf16* __restrict__ xt, const bf16* __restrict__ wq,
                           const float* __restrict__ qkv_b, bf16* __restrict__ attn_out) {
    // LDS: 20480*2 + 16896 + 5120 + 384 = 63360 B  -> 2 blocks/CU
    __shared__ bf16 qn[NT][40];       // normalized q, bf16, row pad 40 (80B, 16B-mult)
    __shared__ bf16 kn[NT][40];       // normalized k
    __shared__ bf16 vT[HD][264];      // v transposed [d][token], pad 264 (528B)
    __shared__ bf16 pbuf[4][16][40];  // per-wave P chunk: 16 queries x 32 keys
    __shared__ float bias_s[96];

    const int h = blockIdx.x, b = blockIdx.y;
    const int tid = threadIdx.x;
    const int lane = tid & 63, w = tid >> 6;
    const int l15 = lane & 15, quad = lane >> 4;

    if (tid < 96) {
        int which = tid >> 5;
        bias_s[tid] = qkv_b[which * DIM + h * HD + (tid & 31)];
    }
    __syncthreads();

    // ---- Phase A: qkv GEMM. Wave w owns tokens [w*64, w*64+64), all 96 outputs j.
    // D[j][tok]: A = Wqkv rows (96 x 384), B = xt tokens (384 x 64). Direct global frag loads.
    f32x4 acc[6][4];
#pragma unroll
    for (int jt = 0; jt < 6; ++jt)
#pragma unroll
        for (int tt = 0; tt < 4; ++tt) acc[jt][tt] = (f32x4){0.f, 0.f, 0.f, 0.f};

    const bf16* xrow[4];
#pragma unroll
    for (int tt = 0; tt < 4; ++tt) {
        int tok = w * 64 + tt * 16 + l15;
        xrow[tt] = xt + (size_t)(b * NT + tok) * DIM + quad * 8;
    }
    const bf16* wrow[6];
#pragma unroll
    for (int jt = 0; jt < 6; ++jt) {
        int jj = jt * 16 + l15;
        int which = jj >> 5;
        wrow[jt] = wq + (size_t)(which * DIM + h * HD + (jj & 31)) * DIM + quad * 8;
    }

#pragma unroll 2
    for (int kc = 0; kc < 12; ++kc) {
        int k0 = kc * 32;
        bf16x8 bfr[4], afr[6];
#pragma unroll
        for (int tt = 0; tt < 4; ++tt) bfr[tt] = *(const bf16x8*)(xrow[tt] + k0);
#pragma unroll
        for (int jt = 0; jt < 6; ++jt) afr[jt] = *(const bf16x8*)(wrow[jt] + k0);
#pragma unroll
        for (int jt = 0; jt < 6; ++jt)
#pragma unroll
            for (int tt = 0; tt < 4; ++tt)
                acc[jt][tt] = MFMA16(afr[jt], bfr[tt], acc[jt][tt]);
    }

    // ---- epilogue: +bias, l2-normalize q,k (cross-quad shfl reduce), write bf16 LDS ----
#pragma unroll
    for (int tt = 0; tt < 4; ++tt) {
        int tok = w * 64 + tt * 16 + l15;  // = D col for this frag
        float v[6][4];
        float sq = 0.f, sk = 0.f;
#pragma unroll
        for (int jt = 0; jt < 6; ++jt)
#pragma unroll
            for (int r = 0; r < 4; ++r) {
                int j = jt * 16 + quad * 4 + r;  // D row
                float t = acc[jt][tt][r] + bias_s[j];
                v[jt][r] = t;
                if (jt < 2) sq += t * t;
                else if (jt < 4) sk += t * t;
            }
        // rows of a token are spread across the 4 quads -> reduce over lane^16, lane^32
        sq += __shfl_xor(sq, 16); sq += __shfl_xor(sq, 32);
        sk += __shfl_xor(sk, 16); sk += __shfl_xor(sk, 32);
        float iq = 1.f / fmaxf(sqrtf(sq), 1e-12f);
        float ik = 1.f / fmaxf(sqrtf(sk), 1e-12f);
#pragma unroll
        for (int jt = 0; jt < 6; ++jt)
#pragma unroll
            for (int r = 0; r < 4; ++r) {
                int j = jt * 16 + quad * 4 + r;
                if (j < 32)      qn[tok][j]      = (bf16)(v[jt][r] * iq);
                else if (j < 64) kn[tok][j - 32] = (bf16)(v[jt][r] * ik);
                else             vT[j - 64][tok] = (bf16)v[jt][r];
            }
    }
    __syncthreads();

    // ---- Phase C: attention. Wave w owns queries [w*64, w*64+64).
    const f32x4 zf = {0.f, 0.f, 0.f, 0.f};
#pragma unroll 1
    for (int qt = 0; qt < 4; ++qt) {
        int nq0 = w * 64 + qt * 16;
        bf16x8 qa = *(const bf16x8*)&qn[nq0 + l15][quad * 8];  // A-frag: m=query
        f32x4 o0 = zf, o1 = zf;
        float ds[4] = {0.f, 0.f, 0.f, 0.f};
#pragma unroll 1
        for (int kt = 0; kt < 8; ++kt) {  // 32 keys per chunk
#pragma unroll
            for (int st = 0; st < 2; ++st) {
                int nk0 = kt * 32 + st * 16;
                bf16x8 kb = *(const bf16x8*)&kn[nk0 + l15][quad * 8];  // B-frag: n=key
                f32x4 s = MFMA16(qa, kb, zf);  // S[row=query][col=key]
#pragma unroll
                for (int r = 0; r < 4; ++r) {
                    float p = __expf(s[r] * SCALE);  // no max-subtract: |logit|<=0.178
                    ds[r] += p;                       // partial denom (this lane's keys)
                    pbuf[w][quad * 4 + r][st * 16 + l15] = (bf16)p;
                }
            }
            // P (C-layout) -> A-layout via LDS round-trip; PV MFMA
            bf16x8 pa  = *(const bf16x8*)&pbuf[w][l15][quad * 8];
            bf16x8 vb0 = *(const bf16x8*)&vT[l15][kt * 32 + quad * 8];
            bf16x8 vb1 = *(const bf16x8*)&vT[16 + l15][kt * 32 + quad * 8];
            o0 = MFMA16(pa, vb0, o0);
            o1 = MFMA16(pa, vb1, o1);
        }
        // full denom per query: reduce over the 16 lanes of each quad
#pragma unroll
        for (int r = 0; r < 4; ++r) {
            ds[r] += __shfl_xor(ds[r], 1);
            ds[r] += __shfl_xor(ds[r], 2);
            ds[r] += __shfl_xor(ds[r], 4);
            ds[r] += __shfl_xor(ds[r], 8);
        }
        bf16* op = attn_out + (size_t)(b * NT + nq0) * DIM + h * HD;
#pragma unroll
        for (int r = 0; r < 4; ++r) {
            float inv = 1.f / ds[r];
            int nq = quad * 4 + r;  // O row = query
            op[(size_t)nq * DIM + l15]      = (bf16)(o0[r] * inv);
            op[(size_t)nq * DIM + 16 + l15] = (bf16)(o1[r] * inv);
        }
    }
}

// ---------------- K3: proj GEMM + output transpose ----------------
__launch_bounds__(256, 2)
__global__ void k_proj(const bf16* __restrict__ xa, const bf16* __restrict__ wp,
                       const float* __restrict__ proj_b, float* __restrict__ out) {
    __shared__ float bias_s[96];
    const int cb = blockIdx.x, b = blockIdx.y;  // cb: 96-wide slice of 384 out channels
    const int tid = threadIdx.x;
    const int lane = tid & 63, w = tid >> 6;
    const int l15 = lane & 15, quad = lane >> 4;
    if (tid < 96) bias_s[tid] = proj_b[cb * 96 + tid];
    __syncthreads();

    f32x4 acc[6][4];
#pragma unroll
    for (int jt = 0; jt < 6; ++jt)
#pragma unroll
        for (int tt = 0; tt < 4; ++tt) acc[jt][tt] = (f32x4){0.f, 0.f, 0.f, 0.f};

    const bf16* arow[6];
#pragma unroll
    for (int jt = 0; jt < 6; ++jt)
        arow[jt] = wp + (size_t)(cb * 96 + jt * 16 + l15) * DIM + quad * 8;
    const bf16* brow[4];
#pragma unroll
    for (int tt = 0; tt < 4; ++tt)
        brow[tt] = xa + (size_t)(b * NT + w * 64 + tt * 16 + l15) * DIM + quad * 8;

#pragma unroll 2
    for (int kc = 0; kc < 12; ++kc) {
        int k0 = kc * 32;
        bf16x8 bfr[4], afr[6];
#pragma unroll
        for (int tt = 0; tt < 4; ++tt) bfr[tt] = *(const bf16x8*)(brow[tt] + k0);
#pragma unroll
        for (int jt = 0; jt < 6; ++jt) afr[jt] = *(const bf16x8*)(arow[jt] + k0);
#pragma unroll
        for (int jt = 0; jt < 6; ++jt)
#pragma unroll
            for (int tt = 0; tt < 4; ++tt)
                acc[jt][tt] = MFMA16(afr[jt], bfr[tt], acc[jt][tt]);
    }

    float* op = out + (size_t)b * DIM * NT;  // out[b][c][n]
#pragma unroll
    for (int jt = 0; jt < 6; ++jt)
#pragma unroll
        for (int tt = 0; tt < 4; ++tt)
#pragma unroll
            for (int r = 0; r < 4; ++r) {
                int cl = jt * 16 + quad * 4 + r;          // D row = out channel (local)
                int n  = w * 64 + tt * 16 + l15;          // D col = token
                op[(size_t)(cb * 96 + cl) * NT + n] = acc[jt][tt][r] + bias_s[cl];
            }
}

extern "C" void kernel_launch(void* const* d_in, const int* in_sizes, int n_in,
                              void* d_out, int out_size, void* d_ws, size_t ws_size,
                              hipStream_t stream) {
    const float* x      = (const float*)d_in[0];
    const float* qkv_w  = (const float*)d_in[1];
    const float* qkv_b  = (const float*)d_in[2];
    const float* proj_w = (const float*)d_in[3];
    const float* proj_b = (const float*)d_in[4];
    float* out = (float*)d_out;

    char* ws = (char*)d_ws;
    bf16* xt = (bf16*)ws;                    // 256*256*384*2 = 50,331,648 B
    bf16* xa = (bf16*)(ws + 50331648);       // 50,331,648 B
    bf16* wq = (bf16*)(ws + 100663296);      // 884,736 B
    bf16* wp = (bf16*)(ws + 101548032);      // 294,912 B  (total 101,842,944 B)

    k_cast_w<<<dim3(1728), dim3(256), 0, stream>>>(qkv_w, proj_w, wq, wp);
    k_transpose_cast<<<dim3(8, 12, 256), dim3(32, 8), 0, stream>>>(x, xt);
    k_qkv_attn<<<dim3(NH, 256), dim3(256), 0, stream>>>(xt, wq, qkv_b, xa);
    k_proj<<<dim3(4, 256), dim3(256), 0, stream>>>(xa, wp, proj_b, out);
}